// Round 3
// baseline (578.407 us; speedup 1.0000x reference)
//
#include <hip/hip_runtime.h>

#define BB 8
#define NN 2048
#define CC 128
#define KSEL 16
#define KMAX 32
#define NEG 0.2f
#define CH 8
#define CHSZ (NN / CH)   // 256

// Map f32 to a u32 whose unsigned order == float order (handles negatives).
__device__ __forceinline__ unsigned int f2key(float f) {
  unsigned int b = __float_as_uint(f);
  return (b & 0x80000000u) ? ~b : (b | 0x80000000u);
}

// np-exact f32 squared norm: fl(fl(x^2+y^2)+z^2), no FMA contraction.
__device__ __forceinline__ float sq3(float x, float y, float z) {
  return __fadd_rn(__fadd_rn(__fmul_rn(x, x), __fmul_rn(y, y)), __fmul_rn(z, z));
}

// np-exact f32 distance key: d2 = fl( fl(sq_i+sq_j) - fl(2*dot) ),
// dot = fma(a2,b2, fma(a1,b1, round(a0*b0)))  (BLAS K-ascending FMA chain).
__device__ __forceinline__ float d2np(float px, float py, float pz, float sqq,
                                      float qx, float qy, float qz, float sqj) {
  float dot = __fmaf_rn(pz, qz, __fmaf_rn(py, qy, __fmul_rn(px, qx)));
  return __fsub_rn(__fadd_rn(sqq, sqj), __fmul_rn(2.0f, dot));
}

// ---------------------------------------------------------------------------
// K1a: KNN phase 1 — chunked candidate selection with np-bit-exact f32 keys.
// One thread per (query, chunk): stable local top-32 of its 256 candidates.
// Block = 256 threads = 32 queries x 8 chunks of one batch. Grid = 512.
// ---------------------------------------------------------------------------
__global__ __launch_bounds__(256) void knn_p1(const float* __restrict__ pos,
                                              unsigned short* __restrict__ cand) {
  __shared__ float sp[NN * 3];
  __shared__ float ssq[NN];
  int b = blockIdx.x >> 6;                       // 64 blocks per batch
  int qbase = (blockIdx.x & 63) * 32;
  const float* pb = pos + (size_t)b * NN * 3;
  for (int t = threadIdx.x; t < NN * 3; t += 256) sp[t] = pb[t];
  __syncthreads();
  for (int t = threadIdx.x; t < NN; t += 256)
    ssq[t] = sq3(sp[t * 3 + 0], sp[t * 3 + 1], sp[t * 3 + 2]);
  __syncthreads();

  int q = qbase + (threadIdx.x >> 3);
  int c = threadIdx.x & 7;
  float px = sp[q * 3 + 0], py = sp[q * 3 + 1], pz = sp[q * 3 + 2];
  float sqq = ssq[q];

  unsigned int ak[KMAX];
  int ai[KMAX];
#pragma unroll
  for (int k = 0; k < KMAX; ++k) { ak[k] = 0xFFFFFFFFu; ai[k] = 0; }

  int j0 = c * CHSZ;
  for (int jj = 0; jj < CHSZ; ++jj) {
    int j = j0 + jj;
    float d2 = d2np(px, py, pz, sqq,
                    sp[j * 3 + 0], sp[j * 3 + 1], sp[j * 3 + 2], ssq[j]);
    unsigned int key = f2key(d2);
    if (j == q) key = 0xFFFFFFFFu;               // exclude self (+1e10 diag)
    if (key < ak[KMAX - 1]) {                    // strict: stable ties -> lower j
#pragma unroll
      for (int k = KMAX - 1; k >= 1; --k) {
        bool ck  = key < ak[k];
        bool ckm = key < ak[k - 1];
        unsigned int tk = ckm ? ak[k - 1] : key;
        int          ti = ckm ? ai[k - 1] : j;
        ak[k] = ck ? tk : ak[k];
        ai[k] = ck ? ti : ai[k];
      }
      bool c0 = key < ak[0];
      ak[0] = c0 ? key : ak[0];
      ai[0] = c0 ? j : ai[0];
    }
  }

  unsigned short* oc = cand + (((size_t)(b * NN + q)) * CH + c) * KMAX;
#pragma unroll
  for (int k = 0; k < KMAX; ++k) oc[k] = (unsigned short)ai[k];
}

// ---------------------------------------------------------------------------
// K1b: KNN phase 2 — stable merge of the 8 chunk lists, same f32 keys.
// Candidate order (chunk-major, rank order within chunk) preserves the global
// stable tie rule (equal keys -> lower index first). One thread per query.
// ---------------------------------------------------------------------------
__global__ __launch_bounds__(64) void knn_p2(const float* __restrict__ pos,
                                             const unsigned short* __restrict__ cand,
                                             int* __restrict__ nbr) {
  __shared__ float sp[NN * 3];
  __shared__ float ssq[NN];
  int b = blockIdx.x >> 5;                       // 32 blocks per batch
  int q = (blockIdx.x & 31) * 64 + threadIdx.x;
  const float* pb = pos + (size_t)b * NN * 3;
  for (int t = threadIdx.x; t < NN * 3; t += 64) sp[t] = pb[t];
  __syncthreads();
  for (int t = threadIdx.x; t < NN; t += 64)
    ssq[t] = sq3(sp[t * 3 + 0], sp[t * 3 + 1], sp[t * 3 + 2]);
  __syncthreads();

  float px = sp[q * 3 + 0], py = sp[q * 3 + 1], pz = sp[q * 3 + 2];
  float sqq = ssq[q];

  unsigned int ak[KMAX];
  int ai[KMAX];
#pragma unroll
  for (int k = 0; k < KMAX; ++k) { ak[k] = 0xFFFFFFFFu; ai[k] = 0; }

  const unsigned short* cq = cand + ((size_t)(b * NN + q)) * (CH * KMAX);
  for (int u = 0; u < CH * KMAX; ++u) {
    int j = (int)cq[u];
    float d2 = d2np(px, py, pz, sqq,
                    sp[j * 3 + 0], sp[j * 3 + 1], sp[j * 3 + 2], ssq[j]);
    unsigned int key = f2key(d2);
    if (j == q) key = 0xFFFFFFFFu;
    if (key < ak[KMAX - 1]) {
#pragma unroll
      for (int k = KMAX - 1; k >= 1; --k) {
        bool ck  = key < ak[k];
        bool ckm = key < ak[k - 1];
        unsigned int tk = ckm ? ak[k - 1] : key;
        int          ti = ckm ? ai[k - 1] : j;
        ak[k] = ck ? tk : ak[k];
        ai[k] = ck ? ti : ai[k];
      }
      bool c0 = key < ak[0];
      ak[0] = c0 ? key : ak[0];
      ai[0] = c0 ? j : ai[0];
    }
  }

  int* onb = nbr + ((size_t)(b * NN + q)) * KMAX;
#pragma unroll
  for (int k = 0; k < KMAX; ++k) onb[k] = ai[k];
}

// ---------------------------------------------------------------------------
// K2: f32 tiled GEMM  out[M=16384][128] = concat(A1[:,0:K1], A2[:,0:K-K1]) @ W
// ---------------------------------------------------------------------------
__global__ __launch_bounds__(256) void gemm_kernel(
    const float* __restrict__ A1, int lda1, int K1,
    const float* __restrict__ A2, int lda2, int K,
    const float* __restrict__ W, const float* __restrict__ bias,
    float* __restrict__ out, int applyLeaky) {
  __shared__ float At[8][64];
  __shared__ float Wt[8][CC];

  int m0 = blockIdx.x * 64;
  int tid = threadIdx.x;
  int cg = tid & 31;
  int rg = tid >> 5;

  float acc[8][4];
#pragma unroll
  for (int r = 0; r < 8; ++r)
#pragma unroll
    for (int q = 0; q < 4; ++q) acc[r][q] = 0.f;

  int ksteps = (K + 7) >> 3;
  for (int ks = 0; ks < ksteps; ++ks) {
    int k0 = ks << 3;
    __syncthreads();
    {
      int f = tid * 2;
      int m = f >> 3;
      int kk = f & 7;
      int gm = m0 + m;
#pragma unroll
      for (int u = 0; u < 2; ++u) {
        int k = k0 + kk + u;
        float v = 0.f;
        if (k < K1) v = A1[(size_t)gm * lda1 + k];
        else if (k < K) v = A2[(size_t)gm * lda2 + (k - K1)];
        At[kk + u][m] = v;
      }
    }
    {
      int kk = tid >> 5;
      int c = (tid & 31) * 4;
      int k = k0 + kk;
      float4 w = make_float4(0.f, 0.f, 0.f, 0.f);
      if (k < K) w = *(const float4*)(W + (size_t)k * CC + c);
      *(float4*)(&Wt[kk][c]) = w;
    }
    __syncthreads();
#pragma unroll
    for (int kk = 0; kk < 8; ++kk) {
      float4 a0 = *(const float4*)(&At[kk][rg * 8]);
      float4 a1 = *(const float4*)(&At[kk][rg * 8 + 4]);
      float4 w = *(const float4*)(&Wt[kk][cg * 4]);
      float a[8] = {a0.x, a0.y, a0.z, a0.w, a1.x, a1.y, a1.z, a1.w};
#pragma unroll
      for (int r = 0; r < 8; ++r) {
        acc[r][0] += a[r] * w.x;
        acc[r][1] += a[r] * w.y;
        acc[r][2] += a[r] * w.z;
        acc[r][3] += a[r] * w.w;
      }
    }
  }

#pragma unroll
  for (int r = 0; r < 8; ++r) {
    int m = m0 + rg * 8 + r;
#pragma unroll
    for (int q = 0; q < 4; ++q) {
      int c = cg * 4 + q;
      float v = acc[r][q];
      if (bias) v += bias[c];
      if (applyLeaky) v = v > 0.f ? v : NEG * v;
      out[(size_t)m * CC + c] = v;
    }
  }
}

// ---------------------------------------------------------------------------
// K3: per-point transformer attention for one dilation; h += sum_j w*(v_j+δ_j)
// ---------------------------------------------------------------------------
__global__ __launch_bounds__(128) void attn_kernel(
    const float* __restrict__ pos, const int* __restrict__ nbr,
    const float* __restrict__ s, const float* __restrict__ v,
    const float* __restrict__ t, const float* __restrict__ Wpos,
    const float* __restrict__ bpos, float* __restrict__ h, int dil) {
  int bn = blockIdx.x;
  int b = bn >> 11;
  int n = bn & (NN - 1);
  int c = threadIdx.x;

  const float* pb = pos + (size_t)b * NN * 3;
  float pix = pb[n * 3 + 0], piy = pb[n * 3 + 1], piz = pb[n * 3 + 2];
  float w0 = Wpos[c], w1 = Wpos[CC + c], w2 = Wpos[2 * CC + c];
  float bp = bpos[c];
  float tc = t[(size_t)bn * CC + c];
  const int* nb = nbr + (size_t)bn * KMAX;

  float alpha[17], del[17];
  float mx = -1e30f;
#pragma unroll
  for (int j = 0; j < 17; ++j) {
    int idx = (j < 16) ? nb[j * dil] : n;
    float dx = pix - pb[idx * 3 + 0];
    float dy = piy - pb[idx * 3 + 1];
    float dz = piz - pb[idx * 3 + 2];
    float d = dx * w0 + dy * w1 + dz * w2 + bp;
    del[j] = d;
    float sc = s[((size_t)(b * NN + idx)) * CC + c];
    float a = tc - sc + d;
    alpha[j] = a;
    mx = fmaxf(mx, a);
  }
  float sum = 0.f;
#pragma unroll
  for (int j = 0; j < 17; ++j) {
    float w = expf(alpha[j] - mx);
    alpha[j] = w;
    sum += w;
  }
  float inv = 1.f / sum;
  float hc = 0.f;
#pragma unroll
  for (int j = 0; j < 17; ++j) {
    int idx = (j < 16) ? nb[j * dil] : n;
    float vc = v[((size_t)(b * NN + idx)) * CC + c];
    hc += alpha[j] * (vc + del[j]);
  }
  h[(size_t)bn * CC + c] += hc * inv;
}

// ---------------------------------------------------------------------------
// K5: out[m][0..2] = g[m] @ W2 + b2 + pos[m].  One wave per point.
// ---------------------------------------------------------------------------
__global__ __launch_bounds__(64) void final_kernel(
    const float* __restrict__ g, const float* __restrict__ W2,
    const float* __restrict__ b2, const float* __restrict__ pos,
    float* __restrict__ out) {
  int m = blockIdx.x;
  int k = threadIdx.x;
  float g0 = g[(size_t)m * CC + k];
  float g1 = g[(size_t)m * CC + 64 + k];
  float p0 = g0 * W2[k * 3 + 0] + g1 * W2[(k + 64) * 3 + 0];
  float p1 = g0 * W2[k * 3 + 1] + g1 * W2[(k + 64) * 3 + 1];
  float p2 = g0 * W2[k * 3 + 2] + g1 * W2[(k + 64) * 3 + 2];
#pragma unroll
  for (int off = 32; off >= 1; off >>= 1) {
    p0 += __shfl_down(p0, off);
    p1 += __shfl_down(p1, off);
    p2 += __shfl_down(p2, off);
  }
  if (k == 0) {
    out[m * 3 + 0] = p0 + b2[0] + pos[m * 3 + 0];
    out[m * 3 + 1] = p1 + b2[1] + pos[m * 3 + 1];
    out[m * 3 + 2] = p2 + b2[2] + pos[m * 3 + 2];
  }
}

extern "C" void kernel_launch(void* const* d_in, const int* in_sizes, int n_in,
                              void* d_out, int out_size, void* d_ws, size_t ws_size,
                              hipStream_t stream) {
  const float* x     = (const float*)d_in[0];
  const float* pos   = (const float*)d_in[1];
  const float* W_lin = (const float*)d_in[2];
  const float* W_src = (const float*)d_in[3];
  const float* W_dst = (const float*)d_in[4];
  const float* W_pos = (const float*)d_in[5];
  const float* b_pos = (const float*)d_in[6];
  const float* Wg    = (const float*)d_in[7];
  const float* bg    = (const float*)d_in[8];
  const float* W1    = (const float*)d_in[9];
  const float* b1    = (const float*)d_in[10];
  const float* W2    = (const float*)d_in[11];
  const float* b2    = (const float*)d_in[12];
  float* out = (float*)d_out;

  const size_t M = (size_t)BB * NN;        // 16384
  const size_t MC = M * CC;                // 2,097,152 floats

  char* ws = (char*)d_ws;
  int* nbr = (int*)ws;                               // M*KMAX ints   = 2 MB
  unsigned short* cand = (unsigned short*)(ws + M * KMAX * sizeof(int));  // 8.4 MB
  float* fb = (float*)(ws + M * KMAX * sizeof(int) + M * CH * KMAX * sizeof(unsigned short));
  float* sb0 = fb;
  float* sb1 = fb + 1 * MC;
  float* vb0 = fb + 2 * MC;
  float* vb1 = fb + 3 * MC;
  float* tb0 = fb + 4 * MC;
  float* tb1 = fb + 5 * MC;
  float* h   = fb + 6 * MC;
  float* g   = fb + 7 * MC;

  // 1. KNN with np-bit-exact f32 distance keys
  knn_p1<<<512, 256, 0, stream>>>(pos, cand);
  knn_p2<<<256, 64, 0, stream>>>(pos, cand, nbr);

  // 2. projections (bias-free, no activation)
  gemm_kernel<<<M / 64, 256, 0, stream>>>(x, CC, CC, nullptr, 0, CC,
                                          W_src + 0 * CC * CC, nullptr, sb0, 0);
  gemm_kernel<<<M / 64, 256, 0, stream>>>(x, CC, CC, nullptr, 0, CC,
                                          W_src + 1 * CC * CC, nullptr, sb1, 0);
  gemm_kernel<<<M / 64, 256, 0, stream>>>(x, CC, CC, nullptr, 0, CC,
                                          W_lin + 0 * CC * CC, nullptr, vb0, 0);
  gemm_kernel<<<M / 64, 256, 0, stream>>>(x, CC, CC, nullptr, 0, CC,
                                          W_lin + 1 * CC * CC, nullptr, vb1, 0);
  gemm_kernel<<<M / 64, 256, 0, stream>>>(x, CC, CC, nullptr, 0, CC,
                                          W_dst + 0 * CC * CC, nullptr, tb0, 0);
  gemm_kernel<<<M / 64, 256, 0, stream>>>(x, CC, CC, nullptr, 0, CC,
                                          W_dst + 1 * CC * CC, nullptr, tb1, 0);

  // 3. h = leaky(concat(x,pos) @ Wg + bg)
  gemm_kernel<<<M / 64, 256, 0, stream>>>(x, CC, CC, pos, 3, CC + 3,
                                          Wg, bg, h, 1);

  // 4. h += attention per dilation
  attn_kernel<<<M, 128, 0, stream>>>(pos, nbr, sb0, vb0, tb0,
                                     W_pos + 0 * 3 * CC, b_pos + 0 * CC, h, 1);
  attn_kernel<<<M, 128, 0, stream>>>(pos, nbr, sb1, vb1, tb1,
                                     W_pos + 1 * 3 * CC, b_pos + 1 * CC, h, 2);

  // 5. g = leaky(h @ W1 + b1)
  gemm_kernel<<<M / 64, 256, 0, stream>>>(h, CC, CC, nullptr, 0, CC,
                                          W1, b1, g, 1);

  // 6. out = g @ W2 + b2 + pos
  final_kernel<<<M, 64, 0, stream>>>(g, W2, b2, pos, out);
}

// Round 6
// 508.052 us; speedup vs baseline: 1.1385x; 1.1385x over previous
//
#include <hip/hip_runtime.h>

#define BB 8
#define NN 2048
#define CC 128
#define KMAX 32
#define NEG 0.2f
#define CH 8
#define CHSZ (NN / CH)   // 256

// Map f32 to a u32 whose unsigned order == float order (handles negatives).
__device__ __forceinline__ unsigned int f2key(float f) {
  unsigned int b = __float_as_uint(f);
  return (b & 0x80000000u) ? ~b : (b | 0x80000000u);
}

// np-exact f32 squared norm: fl(fl(x^2+y^2)+z^2), no FMA contraction.
__device__ __forceinline__ float sq3(float x, float y, float z) {
  return __fadd_rn(__fadd_rn(__fmul_rn(x, x), __fmul_rn(y, y)), __fmul_rn(z, z));
}

// np-exact f32 distance key: d2 = fl( fl(sq_i+sq_j) - fl(2*dot) ),
// dot = fma(a2,b2, fma(a1,b1, round(a0*b0)))  (BLAS K-ascending FMA chain).
__device__ __forceinline__ float d2np(float px, float py, float pz, float sqq,
                                      float qx, float qy, float qz, float sqj) {
  float dot = __fmaf_rn(pz, qz, __fmaf_rn(py, qy, __fmul_rn(px, qx)));
  return __fsub_rn(__fadd_rn(sqq, sqj), __fmul_rn(2.0f, dot));
}

// ---------------------------------------------------------------------------
// K1a: KNN phase 1 — chunked candidate selection with np-bit-exact f32 keys.
// One thread per (query, chunk): stable local top-32 of its 256 candidates.
// Block = 256 threads = 32 queries x 8 chunks of one batch. Grid = 512.
// (verbatim from the R3 passing kernel)
// ---------------------------------------------------------------------------
__global__ __launch_bounds__(256) void knn_p1(const float* __restrict__ pos,
                                              unsigned short* __restrict__ cand) {
  __shared__ float sp[NN * 3];
  __shared__ float ssq[NN];
  int b = blockIdx.x >> 6;                       // 64 blocks per batch
  int qbase = (blockIdx.x & 63) * 32;
  const float* pb = pos + (size_t)b * NN * 3;
  for (int t = threadIdx.x; t < NN * 3; t += 256) sp[t] = pb[t];
  __syncthreads();
  for (int t = threadIdx.x; t < NN; t += 256)
    ssq[t] = sq3(sp[t * 3 + 0], sp[t * 3 + 1], sp[t * 3 + 2]);
  __syncthreads();

  int q = qbase + (threadIdx.x >> 3);
  int c = threadIdx.x & 7;
  float px = sp[q * 3 + 0], py = sp[q * 3 + 1], pz = sp[q * 3 + 2];
  float sqq = ssq[q];

  unsigned int ak[KMAX];
  int ai[KMAX];
#pragma unroll
  for (int k = 0; k < KMAX; ++k) { ak[k] = 0xFFFFFFFFu; ai[k] = 0; }

  int j0 = c * CHSZ;
  for (int jj = 0; jj < CHSZ; ++jj) {
    int j = j0 + jj;
    float d2 = d2np(px, py, pz, sqq,
                    sp[j * 3 + 0], sp[j * 3 + 1], sp[j * 3 + 2], ssq[j]);
    unsigned int key = f2key(d2);
    if (j == q) key = 0xFFFFFFFFu;               // exclude self (+1e10 diag)
    if (key < ak[KMAX - 1]) {                    // strict: stable ties -> lower j
#pragma unroll
      for (int k = KMAX - 1; k >= 1; --k) {
        bool ck  = key < ak[k];
        bool ckm = key < ak[k - 1];
        unsigned int tk = ckm ? ak[k - 1] : key;
        int          ti = ckm ? ai[k - 1] : j;
        ak[k] = ck ? tk : ak[k];
        ai[k] = ck ? ti : ai[k];
      }
      bool c0 = key < ak[0];
      ak[0] = c0 ? key : ak[0];
      ai[0] = c0 ? j : ai[0];
    }
  }

  unsigned short* oc = cand + (((size_t)(b * NN + q)) * CH + c) * KMAX;
#pragma unroll
  for (int k = 0; k < KMAX; ++k) oc[k] = (unsigned short)ai[k];
}

// ---------------------------------------------------------------------------
// K1b: KNN phase 2 — stable merge of the 8 chunk lists, same f32 keys.
// Candidate order (chunk-major, rank order within chunk) preserves the global
// stable tie rule (equal keys -> lower index first). One thread per query.
// (verbatim from the R3 passing kernel)
// ---------------------------------------------------------------------------
__global__ __launch_bounds__(64) void knn_p2(const float* __restrict__ pos,
                                             const unsigned short* __restrict__ cand,
                                             int* __restrict__ nbr) {
  __shared__ float sp[NN * 3];
  __shared__ float ssq[NN];
  int b = blockIdx.x >> 5;                       // 32 blocks per batch
  int q = (blockIdx.x & 31) * 64 + threadIdx.x;
  const float* pb = pos + (size_t)b * NN * 3;
  for (int t = threadIdx.x; t < NN * 3; t += 64) sp[t] = pb[t];
  __syncthreads();
  for (int t = threadIdx.x; t < NN; t += 64)
    ssq[t] = sq3(sp[t * 3 + 0], sp[t * 3 + 1], sp[t * 3 + 2]);
  __syncthreads();

  float px = sp[q * 3 + 0], py = sp[q * 3 + 1], pz = sp[q * 3 + 2];
  float sqq = ssq[q];

  unsigned int ak[KMAX];
  int ai[KMAX];
#pragma unroll
  for (int k = 0; k < KMAX; ++k) { ak[k] = 0xFFFFFFFFu; ai[k] = 0; }

  const unsigned short* cq = cand + ((size_t)(b * NN + q)) * (CH * KMAX);
  for (int u = 0; u < CH * KMAX; ++u) {
    int j = (int)cq[u];
    float d2 = d2np(px, py, pz, sqq,
                    sp[j * 3 + 0], sp[j * 3 + 1], sp[j * 3 + 2], ssq[j]);
    unsigned int key = f2key(d2);
    if (j == q) key = 0xFFFFFFFFu;
    if (key < ak[KMAX - 1]) {
#pragma unroll
      for (int k = KMAX - 1; k >= 1; --k) {
        bool ck  = key < ak[k];
        bool ckm = key < ak[k - 1];
        unsigned int tk = ckm ? ak[k - 1] : key;
        int          ti = ckm ? ai[k - 1] : j;
        ak[k] = ck ? tk : ak[k];
        ai[k] = ck ? ti : ai[k];
      }
      bool c0 = key < ak[0];
      ak[0] = c0 ? key : ak[0];
      ai[0] = c0 ? j : ai[0];
    }
  }

  int* onb = nbr + ((size_t)(b * NN + q)) * KMAX;
#pragma unroll
  for (int k = 0; k < KMAX; ++k) onb[k] = ai[k];
}

// ---------------------------------------------------------------------------
// K2: f32 tiled GEMM  out[M][128] = concat(A1[:,0:K1], A2[:,0:K-K1]) @ W
// ONLY change vs R3: blockIdx.z selects among up to 6 weight matrices
// (Wa[0],Wa[1],Wb[0],Wb[1],Wc[0],Wc[1]) and output slice outbase + z*M*C.
// Launches with gridDim.z==1 behave exactly as the R3 kernel.
// ---------------------------------------------------------------------------
__global__ __launch_bounds__(256) void gemm_kernel(
    const float* __restrict__ A1, int lda1, int K1,
    const float* __restrict__ A2, int lda2, int K,
    const float* __restrict__ Wa, const float* __restrict__ Wb,
    const float* __restrict__ Wc, const float* __restrict__ bias,
    float* __restrict__ outbase, int applyLeaky) {
  __shared__ float At[8][64];
  __shared__ float Wt[8][CC];

  int z = blockIdx.z;
  const float* W = (z < 2) ? (Wa + (size_t)z * CC * CC)
                 : (z < 4) ? (Wb + (size_t)(z - 2) * CC * CC)
                           : (Wc + (size_t)(z - 4) * CC * CC);
  float* out = outbase + (size_t)z * ((size_t)BB * NN * CC);

  int m0 = blockIdx.x * 64;
  int tid = threadIdx.x;
  int cg = tid & 31;
  int rg = tid >> 5;

  float acc[8][4];
#pragma unroll
  for (int r = 0; r < 8; ++r)
#pragma unroll
    for (int q = 0; q < 4; ++q) acc[r][q] = 0.f;

  int ksteps = (K + 7) >> 3;
  for (int ks = 0; ks < ksteps; ++ks) {
    int k0 = ks << 3;
    __syncthreads();
    {
      int f = tid * 2;
      int m = f >> 3;
      int kk = f & 7;
      int gm = m0 + m;
#pragma unroll
      for (int u = 0; u < 2; ++u) {
        int k = k0 + kk + u;
        float v = 0.f;
        if (k < K1) v = A1[(size_t)gm * lda1 + k];
        else if (k < K) v = A2[(size_t)gm * lda2 + (k - K1)];
        At[kk + u][m] = v;
      }
    }
    {
      int kk = tid >> 5;
      int c = (tid & 31) * 4;
      int k = k0 + kk;
      float4 w = make_float4(0.f, 0.f, 0.f, 0.f);
      if (k < K) w = *(const float4*)(W + (size_t)k * CC + c);
      *(float4*)(&Wt[kk][c]) = w;
    }
    __syncthreads();
#pragma unroll
    for (int kk = 0; kk < 8; ++kk) {
      float4 a0 = *(const float4*)(&At[kk][rg * 8]);
      float4 a1 = *(const float4*)(&At[kk][rg * 8 + 4]);
      float4 w = *(const float4*)(&Wt[kk][cg * 4]);
      float a[8] = {a0.x, a0.y, a0.z, a0.w, a1.x, a1.y, a1.z, a1.w};
#pragma unroll
      for (int r = 0; r < 8; ++r) {
        acc[r][0] += a[r] * w.x;
        acc[r][1] += a[r] * w.y;
        acc[r][2] += a[r] * w.z;
        acc[r][3] += a[r] * w.w;
      }
    }
  }

#pragma unroll
  for (int r = 0; r < 8; ++r) {
    int m = m0 + rg * 8 + r;
#pragma unroll
    for (int q = 0; q < 4; ++q) {
      int c = cg * 4 + q;
      float v = acc[r][q];
      if (bias) v += bias[c];
      if (applyLeaky) v = v > 0.f ? v : NEG * v;
      out[(size_t)m * CC + c] = v;
    }
  }
}

// ---------------------------------------------------------------------------
// K3: per-point transformer attention for one dilation; h += sum_j w*(v_j+δ_j)
// (verbatim from the R3 passing kernel)
// ---------------------------------------------------------------------------
__global__ __launch_bounds__(128) void attn_kernel(
    const float* __restrict__ pos, const int* __restrict__ nbr,
    const float* __restrict__ s, const float* __restrict__ v,
    const float* __restrict__ t, const float* __restrict__ Wpos,
    const float* __restrict__ bpos, float* __restrict__ h, int dil) {
  int bn = blockIdx.x;
  int b = bn >> 11;
  int n = bn & (NN - 1);
  int c = threadIdx.x;

  const float* pb = pos + (size_t)b * NN * 3;
  float pix = pb[n * 3 + 0], piy = pb[n * 3 + 1], piz = pb[n * 3 + 2];
  float w0 = Wpos[c], w1 = Wpos[CC + c], w2 = Wpos[2 * CC + c];
  float bp = bpos[c];
  float tc = t[(size_t)bn * CC + c];
  const int* nb = nbr + (size_t)bn * KMAX;

  float alpha[17], del[17];
  float mx = -1e30f;
#pragma unroll
  for (int j = 0; j < 17; ++j) {
    int idx = (j < 16) ? nb[j * dil] : n;
    float dx = pix - pb[idx * 3 + 0];
    float dy = piy - pb[idx * 3 + 1];
    float dz = piz - pb[idx * 3 + 2];
    float d = dx * w0 + dy * w1 + dz * w2 + bp;
    del[j] = d;
    float sc = s[((size_t)(b * NN + idx)) * CC + c];
    float a = tc - sc + d;
    alpha[j] = a;
    mx = fmaxf(mx, a);
  }
  float sum = 0.f;
#pragma unroll
  for (int j = 0; j < 17; ++j) {
    float w = expf(alpha[j] - mx);
    alpha[j] = w;
    sum += w;
  }
  float inv = 1.f / sum;
  float hc = 0.f;
#pragma unroll
  for (int j = 0; j < 17; ++j) {
    int idx = (j < 16) ? nb[j * dil] : n;
    float vc = v[((size_t)(b * NN + idx)) * CC + c];
    hc += alpha[j] * (vc + del[j]);
  }
  h[(size_t)bn * CC + c] += hc * inv;
}

// ---------------------------------------------------------------------------
// K5: out[m][0..2] = g[m] @ W2 + b2 + pos[m].  One wave per point.
// (verbatim from the R3 passing kernel)
// ---------------------------------------------------------------------------
__global__ __launch_bounds__(64) void final_kernel(
    const float* __restrict__ g, const float* __restrict__ W2,
    const float* __restrict__ b2, const float* __restrict__ pos,
    float* __restrict__ out) {
  int m = blockIdx.x;
  int k = threadIdx.x;
  float g0 = g[(size_t)m * CC + k];
  float g1 = g[(size_t)m * CC + 64 + k];
  float p0 = g0 * W2[k * 3 + 0] + g1 * W2[(k + 64) * 3 + 0];
  float p1 = g0 * W2[k * 3 + 1] + g1 * W2[(k + 64) * 3 + 1];
  float p2 = g0 * W2[k * 3 + 2] + g1 * W2[(k + 64) * 3 + 2];
#pragma unroll
  for (int off = 32; off >= 1; off >>= 1) {
    p0 += __shfl_down(p0, off);
    p1 += __shfl_down(p1, off);
    p2 += __shfl_down(p2, off);
  }
  if (k == 0) {
    out[m * 3 + 0] = p0 + b2[0] + pos[m * 3 + 0];
    out[m * 3 + 1] = p1 + b2[1] + pos[m * 3 + 1];
    out[m * 3 + 2] = p2 + b2[2] + pos[m * 3 + 2];
  }
}

extern "C" void kernel_launch(void* const* d_in, const int* in_sizes, int n_in,
                              void* d_out, int out_size, void* d_ws, size_t ws_size,
                              hipStream_t stream) {
  const float* x     = (const float*)d_in[0];
  const float* pos   = (const float*)d_in[1];
  const float* W_lin = (const float*)d_in[2];
  const float* W_src = (const float*)d_in[3];
  const float* W_dst = (const float*)d_in[4];
  const float* W_pos = (const float*)d_in[5];
  const float* b_pos = (const float*)d_in[6];
  const float* Wg    = (const float*)d_in[7];
  const float* bg    = (const float*)d_in[8];
  const float* W1    = (const float*)d_in[9];
  const float* b1    = (const float*)d_in[10];
  const float* W2    = (const float*)d_in[11];
  const float* b2    = (const float*)d_in[12];
  float* out = (float*)d_out;

  const size_t M = (size_t)BB * NN;        // 16384
  const size_t MC = M * CC;                // 2,097,152 floats

  // R3 workspace layout, verbatim (dedicated cand region, no aliasing)
  char* ws = (char*)d_ws;
  int* nbr = (int*)ws;                               // M*KMAX ints   = 2 MB
  unsigned short* cand = (unsigned short*)(ws + M * KMAX * sizeof(int));  // 8.4 MB
  float* fb = (float*)(ws + M * KMAX * sizeof(int) + M * CH * KMAX * sizeof(unsigned short));
  float* sb0 = fb + 0 * MC;
  float* sb1 = fb + 1 * MC;
  float* vb0 = fb + 2 * MC;
  float* vb1 = fb + 3 * MC;
  float* tb0 = fb + 4 * MC;
  float* tb1 = fb + 5 * MC;
  float* h   = fb + 6 * MC;
  float* g   = fb + 7 * MC;

  // 1. KNN with np-bit-exact f32 distance keys (R3 verbatim)
  knn_p1<<<512, 256, 0, stream>>>(pos, cand);
  knn_p2<<<256, 64, 0, stream>>>(pos, cand, nbr);

  // 2. six projections fused in ONE launch (z: sb0,sb1,vb0,vb1,tb0,tb1)
  gemm_kernel<<<dim3(M / 64, 1, 6), 256, 0, stream>>>(
      x, CC, CC, nullptr, 0, CC, W_src, W_lin, W_dst, nullptr, fb, 0);

  // 3. h = leaky(concat(x,pos) @ Wg + bg)
  gemm_kernel<<<dim3(M / 64, 1, 1), 256, 0, stream>>>(
      x, CC, CC, pos, 3, CC + 3, Wg, nullptr, nullptr, bg, h, 1);

  // 4. h += attention per dilation
  attn_kernel<<<M, 128, 0, stream>>>(pos, nbr, sb0, vb0, tb0,
                                     W_pos + 0 * 3 * CC, b_pos + 0 * CC, h, 1);
  attn_kernel<<<M, 128, 0, stream>>>(pos, nbr, sb1, vb1, tb1,
                                     W_pos + 1 * 3 * CC, b_pos + 1 * CC, h, 2);

  // 5. g = leaky(h @ W1 + b1)
  gemm_kernel<<<dim3(M / 64, 1, 1), 256, 0, stream>>>(
      h, CC, CC, nullptr, 0, CC, W1, nullptr, nullptr, b1, g, 1);

  // 6. out = g @ W2 + b2 + pos
  final_kernel<<<M, 64, 0, stream>>>(g, W2, b2, pos, out);
}